// Round 8
// baseline (199.306 us; speedup 1.0000x reference)
//
#include <hip/hip_runtime.h>

// Separable 2D bicubic antialiased resize, scale=0.5 on H and W:
// x: (8,3,1024,1024) fp32 -> out: (8,3,512,512) fp32.
//
// Two-pass split through d_ws: the fused one-kernel variants were
// latency-bound (R4 87us, R5 64us, R6 ~56us; models missed 3x), while the
// harness's own 384MB fill runs at 6.8 TB/s -- so restructure into two pure
// streaming passes, the regime this chip demonstrably saturates.
//   verify : 1 block; checks fov[k][q]==mir(2q-3+k) and per-k weight
//            uniformity for BOTH dims (16K checks); writes flag to d_ws.
//   hpass  : horizontal 8-tap, x(1024x1024) -> h(1024x512) in d_ws.
//            Thread = col-pair x 4 rows: 12 independent float4 loads,
//            64 FMA, 4 coalesced float2 stores. No LDS, no sync.
//   vpass  : vertical 8-tap, h -> out. Thread = 1 col x 4 output rows:
//            14 independent lane-coalesced row loads, 32 FMA, 4 stores.
// Exact table-driven fallback paths are taken (block-uniformly) if flag==0;
// generic kernel for unexpected K or insufficient ws.

#define IH 1024
#define IW 1024
#define OH 512
#define OW 512

__device__ __forceinline__ int mir(int i) {
    i = (i < 0) ? (-1 - i) : i;
    return (i >= IH) ? (2 * IH - 1 - i) : i;   // reflect at 0 / 1024
}

// ---------------- table verification: one block -> flag ----------------
__global__ __launch_bounds__(1024) void verify_tables(
    const float* __restrict__ w0, const int* __restrict__ fov0,
    const float* __restrict__ w1, const int* __restrict__ fov1,
    int* __restrict__ flag)
{
    __shared__ int s_ok;
    if (threadIdx.x == 0) s_ok = 1;
    __syncthreads();
    bool ok = true;
    for (int e = threadIdx.x; e < 8 * OW; e += 1024) {   // 4096 entries/dim
        const int k = e >> 9, q = e & 511;
        const int m = mir(2 * q - 3 + k);
        ok &= (fov1[e] == m) & (w1[e] == w1[k << 9]);    // taps + uniformity
        ok &= (fov0[e] == m) & (w0[e] == w0[k << 9]);    // OH==512 too
    }
    if (!ok) s_ok = 0;                                   // benign same-value race
    __syncthreads();
    if (threadIdx.x == 0) *flag = s_ok;
}

// ---------------- pass 1: horizontal resize x -> h ----------------
// grid (256, 1, nbc), block 256. Thread t -> output cols (2t, 2t+1),
// rows r0..r0+3. Window cols 4t-4 .. 4t+7 (3 float4, aligned).
__global__ __launch_bounds__(256) void hpass(
    const float* __restrict__ x, const float* __restrict__ w1,
    const int* __restrict__ fov1, float* __restrict__ h,
    const int* __restrict__ flag)
{
    const int t  = threadIdx.x;
    const int r0 = blockIdx.x * 4;
    const int bc = blockIdx.z;
    const float* __restrict__ xp = x + (size_t)bc * (IH * IW);
    float*       __restrict__ hp = h + (size_t)bc * (IH * OW);

    if (*flag) {
        float wx[8];
#pragma unroll
        for (int k = 0; k < 8; ++k) wx[k] = w1[k * OW];   // block-uniform
        const int gc = 4 * t - 4;
        float4 A[4], B[4], C[4];
#pragma unroll
        for (int rr = 0; rr < 4; ++rr) {
            const float* rp = xp + (size_t)(r0 + rr) * IW;
            if (gc >= 0 && gc + 12 <= IW) {               // interior lanes
                A[rr] = *reinterpret_cast<const float4*>(rp + gc);
                B[rr] = *reinterpret_cast<const float4*>(rp + gc + 4);
                C[rr] = *reinterpret_cast<const float4*>(rp + gc + 8);
            } else {                                      // lanes t=0, t=255
                A[rr].x = rp[mir(gc +  0)]; A[rr].y = rp[mir(gc +  1)];
                A[rr].z = rp[mir(gc +  2)]; A[rr].w = rp[mir(gc +  3)];
                B[rr].x = rp[mir(gc +  4)]; B[rr].y = rp[mir(gc +  5)];
                B[rr].z = rp[mir(gc +  6)]; B[rr].w = rp[mir(gc +  7)];
                C[rr].x = rp[mir(gc +  8)]; C[rr].y = rp[mir(gc +  9)];
                C[rr].z = rp[mir(gc + 10)]; C[rr].w = rp[mir(gc + 11)];
            }
        }
#pragma unroll
        for (int rr = 0; rr < 4; ++rr) {
            const float v[12] = { A[rr].x, A[rr].y, A[rr].z, A[rr].w,
                                  B[rr].x, B[rr].y, B[rr].z, B[rr].w,
                                  C[rr].x, C[rr].y, C[rr].z, C[rr].w };
            float h0 = wx[0] * v[1];
            float h1 = wx[0] * v[3];
#pragma unroll
            for (int k = 1; k < 8; ++k) {
                h0 = fmaf(wx[k], v[1 + k], h0);
                h1 = fmaf(wx[k], v[3 + k], h1);
            }
            *reinterpret_cast<float2*>(&hp[(size_t)(r0 + rr) * OW + 2 * t]) =
                make_float2(h0, h1);
        }
    } else {
        // exact table-driven fallback (block-uniform branch)
        for (int rr = 0; rr < 4; ++rr) {
            const float* rp = xp + (size_t)(r0 + rr) * IW;
            for (int s = 0; s < 2; ++s) {
                const int q = 2 * t + s;
                float hv = 0.f;
                for (int k = 0; k < 8; ++k)
                    hv = fmaf(w1[k * OW + q], rp[fov1[k * OW + q]], hv);
                hp[(size_t)(r0 + rr) * OW + q] = hv;
            }
        }
    }
}

// ---------------- pass 2: vertical resize h -> out ----------------
// grid (8, 32, nbc), block 256. Wave-uniform 4-row group per wave slot,
// lane -> col. 14 independent coalesced row loads per thread.
__global__ __launch_bounds__(256) void vpass(
    const float* __restrict__ h, const float* __restrict__ w0,
    const int* __restrict__ fov0, float* __restrict__ out,
    const int* __restrict__ flag)
{
    const int lane = threadIdx.x & 63;
    const int wid  = threadIdx.x >> 6;
    const int q    = blockIdx.x * 64 + lane;
    const int oh0  = blockIdx.y * 16 + wid * 4;
    const int bc   = blockIdx.z;
    const float* __restrict__ hp = h + (size_t)bc * (IH * OW);
    float*       __restrict__ op = out + (size_t)bc * (OH * OW);

    if (*flag) {
        float wy[8];
#pragma unroll
        for (int k = 0; k < 8; ++k) wy[k] = w0[k * OH];   // block-uniform
        const int rb = 2 * oh0 - 3;
        float v[14];
#pragma unroll
        for (int i = 0; i < 14; ++i)
            v[i] = hp[(size_t)mir(rb + i) * OW + q];      // mir: wave-uniform
        float acc[4];
#pragma unroll
        for (int r = 0; r < 4; ++r) {
            float a = wy[0] * v[2 * r];
#pragma unroll
            for (int k = 1; k < 8; ++k)
                a = fmaf(wy[k], v[2 * r + k], a);
            acc[r] = a;
        }
#pragma unroll
        for (int r = 0; r < 4; ++r)
            op[(size_t)(oh0 + r) * OW + q] = acc[r];
    } else {
        // exact table-driven fallback over h (h itself exact when flag==0)
        for (int r = 0; r < 4; ++r) {
            const int oh = oh0 + r;
            float a = 0.f;
            for (int k = 0; k < 8; ++k)
                a = fmaf(w0[k * OH + oh],
                         hp[(size_t)fov0[k * OH + oh] * OW + q], a);
            op[(size_t)oh * OW + q] = a;
        }
    }
}

// ---------------- generic fallback (any K, or ws too small) ----------------
__global__ __launch_bounds__(256) void resize_gen(
    const float* __restrict__ x,
    const float* __restrict__ w0, const int* __restrict__ fov0,
    const float* __restrict__ w1, const int* __restrict__ fov1,
    float* __restrict__ out, int K0, int K1)
{
    const int ow = blockIdx.x * 64 + threadIdx.x;
    const int oh = blockIdx.y * 4 + threadIdx.y;
    const int bc = blockIdx.z;
    const float* __restrict__ xp = x + (size_t)bc * (IH * IW);

    float acc = 0.f;
    for (int k0 = 0; k0 < K0; ++k0) {
        const float wyk = w0[k0 * OH + oh];
        const float* __restrict__ rp = xp + (size_t)fov0[k0 * OH + oh] * IW;
        float hsum = 0.f;
        for (int k1 = 0; k1 < K1; ++k1)
            hsum = fmaf(w1[k1 * OW + ow], rp[fov1[k1 * OW + ow]], hsum);
        acc = fmaf(wyk, hsum, acc);
    }
    out[(size_t)bc * (OH * OW) + (size_t)oh * OW + ow] = acc;
}

extern "C" void kernel_launch(void* const* d_in, const int* in_sizes, int n_in,
                              void* d_out, int out_size, void* d_ws, size_t ws_size,
                              hipStream_t stream)
{
    const float* x    = (const float*)d_in[0];
    const float* w0   = (const float*)d_in[1];
    const int*   fov0 = (const int*)d_in[2];
    const float* w1   = (const float*)d_in[3];
    const int*   fov1 = (const int*)d_in[4];
    float* out = (float*)d_out;

    const int nbc = in_sizes[0] / (IH * IW);
    const int K0  = in_sizes[1] / OH;
    const int K1  = in_sizes[3] / OW;
    const size_t need = 4096 + (size_t)nbc * IH * OW * sizeof(float);

    if (K0 == 8 && K1 == 8 && ws_size >= need) {
        int*   flag = (int*)d_ws;
        float* h    = (float*)((char*)d_ws + 4096);
        verify_tables<<<1, 1024, 0, stream>>>(w0, fov0, w1, fov1, flag);
        hpass<<<dim3(256, 1, nbc), 256, 0, stream>>>(x, w1, fov1, h, flag);
        vpass<<<dim3(8, 32, nbc), 256, 0, stream>>>(h, w0, fov0, out, flag);
    } else {
        dim3 block(64, 4, 1);
        dim3 grid(OW / 64, OH / 4, nbc);
        resize_gen<<<grid, block, 0, stream>>>(x, w0, fov0, w1, fov1, out, K0, K1);
    }
}

// Round 10
// 165.974 us; speedup vs baseline: 1.2008x; 1.2008x over previous
//
#include <hip/hip_runtime.h>

// Separable 2D bicubic antialiased resize, scale=0.5 on H and W:
// x: (8,3,1024,1024) fp32 -> out: (8,3,512,512) fp32.
//
// R4-R8 empirical law: store-only streams run at 6.8 TB/s but EVERY
// load-containing kernel lands at 1.3-2.2 TB/s effective with all pipes
// idle -- so minimize instructions/byte and total HBM traffic. Fused
// one-kernel design (126 MB traffic, vs 225 MB for the R8 split):
//   verify : 1 block; fov[k][q]==mir(2q-3+k) + weight uniformity -> flag.
//   fused  : per 128x16 output tile: phase A computes 38x128 horizontal
//            8-tap sums h into LDS (thread: 8 h from 6 independent float4,
//            1.5x load redundancy, 2 float4 LDS writes); phase B does the
//            vertical 8-tap from LDS (10 ds_read_b128 -> 2 rows x 4 cols,
//            float4 FMA, float4 stores).
// Exact fallbacks: flag==0 -> table-driven gather; odd K -> generic kernel.

#define IH 1024
#define IW 1024
#define OH 512
#define OW 512

#define TOC 128            // output cols per tile
#define TOR 16             // output rows per tile
#define HR  38             // h rows staged = 2*TOR + 6
#define CHUNKS (TOC / 8)   // 16 col-chunks per h row
#define NTASK (HR * CHUNKS) // 608 phase-A tasks

__device__ __forceinline__ int mir(int i) {
    i = (i < 0) ? (-1 - i) : i;
    return (i >= IH) ? (2 * IH - 1 - i) : i;   // reflect at 0 / 1024
}

// ---------------- table verification: one block -> flag ----------------
__global__ __launch_bounds__(1024) void verify_tables(
    const float* __restrict__ w0, const int* __restrict__ fov0,
    const float* __restrict__ w1, const int* __restrict__ fov1,
    int* __restrict__ flag)
{
    __shared__ int s_ok;
    if (threadIdx.x == 0) s_ok = 1;
    __syncthreads();
    bool ok = true;
    for (int e = threadIdx.x; e < 8 * OW; e += 1024) {   // 4096 entries/dim
        const int k = e >> 9, q = e & 511;
        const int m = mir(2 * q - 3 + k);
        ok &= (fov1[e] == m) & (w1[e] == w1[k << 9]);    // taps + uniformity
        ok &= (fov0[e] == m) & (w0[e] == w0[k << 9]);    // OH==512 too
    }
    if (!ok) s_ok = 0;                                   // benign same-value race
    __syncthreads();
    if (threadIdx.x == 0) *flag = s_ok;
}

// ---------------- fused resize: one 128x16 output tile per block --------
__global__ __launch_bounds__(256) void resize_fused2(
    const float* __restrict__ x,
    const float* __restrict__ w0, const int* __restrict__ fov0,
    const float* __restrict__ w1, const int* __restrict__ fov1,
    float* __restrict__ out, const int* __restrict__ flag)
{
    __shared__ float hbuf[HR][TOC];   // 19456 B

    const int tid = threadIdx.x;
    const int c0  = blockIdx.x * TOC;
    const int r0  = blockIdx.y * TOR;
    const int bc  = blockIdx.z;
    const float* __restrict__ xp = x + (size_t)bc * (IH * IW);
    float*       __restrict__ op = out + (size_t)bc * (OH * OW);

    const int cg  = tid & 31;          // phase-B col group (4 cols)
    const int rg  = tid >> 5;          // phase-B row group (2 out rows)
    const int oh0 = r0 + 2 * rg;

    if (*flag) {
        // block-uniform tap weights (validated by verify_tables)
        float wx[8], wy[8];
#pragma unroll
        for (int k = 0; k < 8; ++k) { wx[k] = w1[k * OW]; wy[k] = w0[k * OH]; }

        const int rowBase = 2 * r0 - 3;

        // ---- phase A: horizontal 8-tap, 8 h per task from 6 float4 loads
#pragma unroll
        for (int it = 0; it < 3; ++it) {
            const int idx = tid + it * 256;
            if (idx < NTASK) {
                const int r  = idx >> 4;          // h row 0..37
                const int ch = idx & 15;          // col chunk (8 out cols)
                const int gr = mir(rowBase + r);
                const int gc = 2 * (c0 + 8 * ch) - 4;   // float4-aligned
                const float* rp = xp + (size_t)gr * IW;
                float v[24];
                if (gc >= 0 && gc + 24 <= IW) {   // interior chunk
                    const float4 L0 = *reinterpret_cast<const float4*>(rp + gc);
                    const float4 L1 = *reinterpret_cast<const float4*>(rp + gc + 4);
                    const float4 L2 = *reinterpret_cast<const float4*>(rp + gc + 8);
                    const float4 L3 = *reinterpret_cast<const float4*>(rp + gc + 12);
                    const float4 L4 = *reinterpret_cast<const float4*>(rp + gc + 16);
                    const float4 L5 = *reinterpret_cast<const float4*>(rp + gc + 20);
                    v[ 0]=L0.x; v[ 1]=L0.y; v[ 2]=L0.z; v[ 3]=L0.w;
                    v[ 4]=L1.x; v[ 5]=L1.y; v[ 6]=L1.z; v[ 7]=L1.w;
                    v[ 8]=L2.x; v[ 9]=L2.y; v[10]=L2.z; v[11]=L2.w;
                    v[12]=L3.x; v[13]=L3.y; v[14]=L3.z; v[15]=L3.w;
                    v[16]=L4.x; v[17]=L4.y; v[18]=L4.z; v[19]=L4.w;
                    v[20]=L5.x; v[21]=L5.y; v[22]=L5.z; v[23]=L5.w;
                } else {                          // image-edge chunk: mirror
#pragma unroll
                    for (int j = 0; j < 24; ++j) v[j] = rp[mir(gc + j)];
                }
                float h[8];
#pragma unroll
                for (int m = 0; m < 8; ++m) {
                    float a = wx[0] * v[2 * m + 1];
#pragma unroll
                    for (int k = 1; k < 8; ++k)
                        a = fmaf(wx[k], v[2 * m + 1 + k], a);
                    h[m] = a;
                }
                *reinterpret_cast<float4*>(&hbuf[r][8 * ch]) =
                    make_float4(h[0], h[1], h[2], h[3]);
                *reinterpret_cast<float4*>(&hbuf[r][8 * ch + 4]) =
                    make_float4(h[4], h[5], h[6], h[7]);
            }
        }
        __syncthreads();

        // ---- phase B: vertical 8-tap from LDS, 2 out rows x 4 cols/thread
        const int lr0 = 4 * rg;
        float4 a0 = make_float4(0.f, 0.f, 0.f, 0.f);
        float4 a1 = make_float4(0.f, 0.f, 0.f, 0.f);
#pragma unroll
        for (int i = 0; i < 10; ++i) {
            const float4 rv = *reinterpret_cast<const float4*>(&hbuf[lr0 + i][4 * cg]);
            if (i < 8) {
                const float w = wy[i];
                a0.x = fmaf(w, rv.x, a0.x); a0.y = fmaf(w, rv.y, a0.y);
                a0.z = fmaf(w, rv.z, a0.z); a0.w = fmaf(w, rv.w, a0.w);
            }
            if (i >= 2) {
                const float w = wy[i - 2];
                a1.x = fmaf(w, rv.x, a1.x); a1.y = fmaf(w, rv.y, a1.y);
                a1.z = fmaf(w, rv.z, a1.z); a1.w = fmaf(w, rv.w, a1.w);
            }
        }
        *reinterpret_cast<float4*>(&op[(size_t)oh0 * OW + c0 + 4 * cg]) = a0;
        *reinterpret_cast<float4*>(&op[(size_t)(oh0 + 1) * OW + c0 + 4 * cg]) = a1;
    } else {
        // ---- exact fallback: table-driven 64-tap gather (same 8 outputs)
        for (int rr = 0; rr < 2; ++rr) {
            const int oh = oh0 + rr;
            for (int cc = 0; cc < 4; ++cc) {
                const int q = c0 + 4 * cg + cc;
                float a = 0.f;
                for (int k0 = 0; k0 < 8; ++k0) {
                    const float* rp = xp + (size_t)fov0[k0 * OH + oh] * IW;
                    float hs = 0.f;
                    for (int k1 = 0; k1 < 8; ++k1)
                        hs = fmaf(w1[k1 * OW + q], rp[fov1[k1 * OW + q]], hs);
                    a = fmaf(w0[k0 * OH + oh], hs, a);
                }
                op[(size_t)oh * OW + q] = a;
            }
        }
    }
}

// ---------------- generic fallback (any K, or ws too small) ----------------
__global__ __launch_bounds__(256) void resize_gen(
    const float* __restrict__ x,
    const float* __restrict__ w0, const int* __restrict__ fov0,
    const float* __restrict__ w1, const int* __restrict__ fov1,
    float* __restrict__ out, int K0, int K1)
{
    const int ow = blockIdx.x * 64 + threadIdx.x;
    const int oh = blockIdx.y * 4 + threadIdx.y;
    const int bc = blockIdx.z;
    const float* __restrict__ xp = x + (size_t)bc * (IH * IW);

    float acc = 0.f;
    for (int k0 = 0; k0 < K0; ++k0) {
        const float wyk = w0[k0 * OH + oh];
        const float* __restrict__ rp = xp + (size_t)fov0[k0 * OH + oh] * IW;
        float hsum = 0.f;
        for (int k1 = 0; k1 < K1; ++k1)
            hsum = fmaf(w1[k1 * OW + ow], rp[fov1[k1 * OW + ow]], hsum);
        acc = fmaf(wyk, hsum, acc);
    }
    out[(size_t)bc * (OH * OW) + (size_t)oh * OW + ow] = acc;
}

extern "C" void kernel_launch(void* const* d_in, const int* in_sizes, int n_in,
                              void* d_out, int out_size, void* d_ws, size_t ws_size,
                              hipStream_t stream)
{
    const float* x    = (const float*)d_in[0];
    const float* w0   = (const float*)d_in[1];
    const int*   fov0 = (const int*)d_in[2];
    const float* w1   = (const float*)d_in[3];
    const int*   fov1 = (const int*)d_in[4];
    float* out = (float*)d_out;

    const int nbc = in_sizes[0] / (IH * IW);
    const int K0  = in_sizes[1] / OH;
    const int K1  = in_sizes[3] / OW;

    if (K0 == 8 && K1 == 8 && ws_size >= 4096) {
        int* flag = (int*)d_ws;
        verify_tables<<<1, 1024, 0, stream>>>(w0, fov0, w1, fov1, flag);
        dim3 grid(OW / TOC, OH / TOR, nbc);   // (4, 32, 24)
        resize_fused2<<<grid, 256, 0, stream>>>(x, w0, fov0, w1, fov1, out, flag);
    } else {
        dim3 block(64, 4, 1);
        dim3 grid(OW / 64, OH / 4, nbc);
        resize_gen<<<grid, block, 0, stream>>>(x, w0, fov0, w1, fov1, out, K0, K1);
    }
}